// Round 13
// baseline (68.540 us; speedup 1.0000x reference)
//
#include <hip/hip_runtime.h>
#include <cstdint>
#include <cstddef>

// Problem constants (K=2048 tokens, D=128 feat, E=64 hidden)
#define KTOT 2048
#define DDIM 128
#define EDIM 64
#define RPB  2    // output rows per edge block (full j-range per block)
#define KPB  4    // z-rows per block in projection kernel

#define LOG2E 1.44269504088896f

typedef float v2f __attribute__((ext_vector_type(2)));

// ---------------------------------------------------------------------------
// Kernel A: per row k and unit e (log2-domain t = (z@W1+b)*log2e):
//   hiw[k,e] = t_i * w2[e]      Ei[k,e] = 2^-t_i        (i-side)
//   hjw[k,e] = t_j * w2[e]      Ej[k,e] = 2^-t_j        (j-side)
// Separate flat tables (R12's interleave regressed: worse per-inst
// coalescing). Edge algebra: silu-dot = sum_e (hiw+hjw)/(1 + Ei*Ej).
// b2 is a row-constant in the logits -> cancels in softmax -> skipped.
// ---------------------------------------------------------------------------
__global__ void proj_kernel(const float* __restrict__ z,
                            const float* __restrict__ W1,
                            const float* __restrict__ b1,
                            const float* __restrict__ w2,
                            float* __restrict__ hiw, float* __restrict__ Ei,
                            float* __restrict__ hjw, float* __restrict__ Ej) {
  __shared__ float zrow[KPB][DDIM];
  const int t  = threadIdx.x;            // 0..127
  const int k0 = blockIdx.x * KPB;
#pragma unroll
  for (int r = 0; r < KPB; ++r) zrow[r][t] = z[(size_t)(k0 + r) * DDIM + t];
  __syncthreads();

  const int  e    = t & 63;
  const bool isHj = (t >= 64);           // wave-uniform (wave0 = i, wave1 = j)
  const float* Wcol = W1 + (isHj ? DDIM * EDIM : 0) + e;

  float acc[KPB];
  const float binit = isHj ? 0.0f : b1[e];
#pragma unroll
  for (int r = 0; r < KPB; ++r) acc[r] = binit;

#pragma unroll 4
  for (int d = 0; d < DDIM; ++d) {
    const float w = Wcol[(size_t)d * EDIM];   // coalesced 256B per wave
#pragma unroll
    for (int r = 0; r < KPB; ++r) acc[r] = fmaf(zrow[r][d], w, acc[r]);
  }

  const float wv = w2[e];
  float* dw = isHj ? hjw : hiw;
  float* dE = isHj ? Ej  : Ei;
#pragma unroll
  for (int r = 0; r < KPB; ++r) {
    const float tv = acc[r] * LOG2E;
    dw[(size_t)(k0 + r) * EDIM + e] = tv * wv;
    dE[(size_t)(k0 + r) * EDIM + e] = __builtin_amdgcn_exp2f(-tv);
  }
}

// ---------------------------------------------------------------------------
// Quad numerator/denominator (NO transcendentals):
//   u_k = hiw_k + hjw_k  (pk_add);  d_k = 1 + Ei_k*Ej_k  (pk_fma)
//   (Nq, Dq) s.t. sum_k u_k/d_k = Nq/Dq over the 4 elements.
// ---------------------------------------------------------------------------
__device__ __forceinline__ void quad_nd(const float4 hw, const float4 he,
                                        const float4 jw, const float4 je,
                                        float& Nq, float& Dq) {
  const v2f u01 = (v2f){hw.x, hw.y} + (v2f){jw.x, jw.y};
  const v2f u23 = (v2f){hw.z, hw.w} + (v2f){jw.z, jw.w};
  const v2f d01 = (v2f){he.x, he.y} * (v2f){je.x, je.y} + 1.0f;  // pk_fma
  const v2f d23 = (v2f){he.z, he.w} * (v2f){je.z, je.w} + 1.0f;
  const float n01 = fmaf(u01.x, d01.y, u01.y * d01.x);
  const float n23 = fmaf(u23.x, d23.y, u23.y * d23.x);
  const float p01 = d01.x * d01.y;
  const float p23 = d23.x * d23.y;
  Nq = fmaf(n01, p23, n23 * p01);
  Dq = p01 * p23;
}

// ---------------------------------------------------------------------------
// DPP butterfly sum over each aligned 8-lane group (no LDS pipe):
// xor1 = quad_perm[1,0,3,2] (0xB1); xor2 = quad_perm[2,3,0,1] (0x4E);
// then row_half_mirror (0x141): lane^7 supplies the other quad's sum.
// All 8 lanes end holding the full octet sum.
// ---------------------------------------------------------------------------
__device__ __forceinline__ float dpp_red8(float a) {
  int t;
  t = __builtin_amdgcn_update_dpp(0, __float_as_int(a), 0xB1, 0xF, 0xF, true);
  a += __int_as_float(t);
  t = __builtin_amdgcn_update_dpp(0, __float_as_int(a), 0x4E, 0xF, 0xF, true);
  a += __int_as_float(t);
  t = __builtin_amdgcn_update_dpp(0, __float_as_int(a), 0x141, 0xF, 0xF, true);
  a += __int_as_float(t);
  return a;
}

// ---------------------------------------------------------------------------
// Kernel B: one kernel does edges + full softmax. grid = 1024 blocks =
// KTOT/RPB i-groups; each block owns RPB=2 full output rows (all 2048 j).
// 256 threads (4 waves); __launch_bounds__(256,4) = cap 128, spill-proof
// (R7/R8 lesson). RPB=2 keeps fragments at 8 float4 = 32 VGPR so the
// compiler keeps them truly live (R10's RPB=4 was silently rematerializing).
// Lane layout: sub = lane&7 -> e-octet; jg = lane>>3 -> one of 8 j's/wave.
// 4 waves x 8 j = 32 j/iter -> 64 iters. Register double-buffer prefetch.
// Main loop: 2 quad_nd chains + own rcp per row; DPP 3-add reduce; exp2
// IN-LOOP (max-free, log2-domain); unnormalized ev stored straight to out
// (32B contiguous per store); row-sum accumulated in registers (each ev
// counted 8x -> rinv = 8/S). Epilogue: 6-shfl + tiny-LDS cross-wave sum,
// then each block rescales its OWN 16KB tile (same CU -> L1/L2-hot RMW).
// This deletes the norm kernel's 32MB HBM round-trip AND the logits LDS.
// ---------------------------------------------------------------------------
__global__ __launch_bounds__(256, 4) void edge_kernel(
    const float* __restrict__ hiw_, const float* __restrict__ Ei_,
    const float* __restrict__ hjw_, const float* __restrict__ Ej_,
    float* __restrict__ out) {
  __shared__ float ps[4][RPB];           // cross-wave sum partials

  const int tid  = threadIdx.x;
  const int lane = tid & 63;
  const int wave = tid >> 6;             // 0..3
  const int sub  = lane & 7;             // e-octet index
  const int jg   = lane >> 3;            // 0..7
  const int i0   = blockIdx.x * RPB;

  // Row-constant fragments: 8 float4 = 32 VGPR
  float4 hwA[RPB], hwB[RPB], heA[RPB], heB[RPB];
#pragma unroll
  for (int r = 0; r < RPB; ++r) {
    const size_t o = (size_t)(i0 + r) * EDIM + sub * 8;
    hwA[r] = *reinterpret_cast<const float4*>(hiw_ + o);
    hwB[r] = *reinterpret_cast<const float4*>(hiw_ + o + 4);
    heA[r] = *reinterpret_cast<const float4*>(Ei_ + o);
    heB[r] = *reinterpret_cast<const float4*>(Ei_ + o + 4);
  }

  const int jloc = wave * 8 + jg;        // this lane's j at iter 0 (0..31)
  const float* pjw = hjw_ + (size_t)jloc * EDIM + sub * 8;
  const float* pje = Ej_  + (size_t)jloc * EDIM + sub * 8;

  float4 jwA = *reinterpret_cast<const float4*>(pjw);
  float4 jwB = *reinterpret_cast<const float4*>(pjw + 4);
  float4 jeA = *reinterpret_cast<const float4*>(pje);
  float4 jeB = *reinterpret_cast<const float4*>(pje + 4);

  float ssum[RPB] = {0.0f, 0.0f};
  float* orow0 = out + (size_t)i0 * KTOT;

  for (int it = 0; it < KTOT / 32; ++it) {
    const float4 cwA = jwA, cwB = jwB, ceA = jeA, ceB = jeB;
    if (it + 1 < KTOT / 32) {            // prefetch next j-row under compute
      const size_t off = (size_t)(it + 1) * 32 * EDIM;
      jwA = *reinterpret_cast<const float4*>(pjw + off);
      jwB = *reinterpret_cast<const float4*>(pjw + off + 4);
      jeA = *reinterpret_cast<const float4*>(pje + off);
      jeB = *reinterpret_cast<const float4*>(pje + off + 4);
    }
    const int j = jloc + it * 32;
#pragma unroll
    for (int r = 0; r < RPB; ++r) {
      float N0, D0, N1, D1;
      quad_nd(hwA[r], heA[r], cwA, ceA, N0, D0);
      quad_nd(hwB[r], heB[r], cwB, ceB, N1, D1);
      const float rD = __builtin_amdgcn_rcpf(D0 * D1);
      float a = fmaf(N0, D1, N1 * D0) * rD;
      a = dpp_red8(a);                   // all 8 lanes hold the octet sum
      const float ev = __builtin_amdgcn_exp2f(a);  // log2-domain, unshifted
      ssum[r] += ev;                     // each ev counted 8x across lanes
      if (sub == 0) orow0[(size_t)r * KTOT + j] = ev;  // 8 lanes -> 32B run
    }
  }

  // Cross-lane + cross-wave row-sum reduce.
#pragma unroll
  for (int r = 0; r < RPB; ++r)
#pragma unroll
    for (int off = 32; off; off >>= 1) ssum[r] += __shfl_xor(ssum[r], off);
  if (lane == 0) {
#pragma unroll
    for (int r = 0; r < RPB; ++r) ps[wave][r] = ssum[r];
  }
  __syncthreads();

  // Rescale own tile (L1/L2-hot: same CU wrote it). wave -> row (w>>1),
  // half (w&1) of 1024 elems; 4 float4 per lane, coalesced 1KB/wave.
  const int r = wave >> 1;
  const int h = wave & 1;
  const float S = (ps[0][r] + ps[1][r]) + (ps[2][r] + ps[3][r]);
  const float rinv = 8.0f * __builtin_amdgcn_rcpf(S);  // 8x overcount
  float* orow = out + (size_t)(i0 + r) * KTOT + h * 1024;
#pragma unroll
  for (int t = 0; t < 4; ++t) {
    float4 v = *reinterpret_cast<const float4*>(&orow[t * 256 + lane * 4]);
    v.x *= rinv; v.y *= rinv; v.z *= rinv; v.w *= rinv;
    *reinterpret_cast<float4*>(&orow[t * 256 + lane * 4]) = v;
  }
}

// ---------------------------------------------------------------------------
extern "C" void kernel_launch(void* const* d_in, const int* in_sizes, int n_in,
                              void* d_out, int out_size, void* d_ws, size_t ws_size,
                              hipStream_t stream) {
  const float* z  = (const float*)d_in[0];
  const float* W1 = (const float*)d_in[1];
  const float* b1 = (const float*)d_in[2];
  const float* W2 = (const float*)d_in[3];
  // d_in[4] = b2: uniform logit shift, cancels in softmax.
  float* out = (float*)d_out;

  float* hiw = (float*)d_ws;                      // 4 tables x 512 KB
  float* Ei  = hiw + (size_t)KTOT * EDIM;
  float* hjw = Ei  + (size_t)KTOT * EDIM;
  float* Ej  = hjw + (size_t)KTOT * EDIM;

  hipLaunchKernelGGL(proj_kernel, dim3(KTOT / KPB), dim3(DDIM), 0, stream,
                     z, W1, b1, W2, hiw, Ei, hjw, Ej);
  hipLaunchKernelGGL(edge_kernel, dim3(KTOT / RPB), dim3(256), 0, stream,
                     hiw, Ei, hjw, Ej, out);
}